// Round 1
// baseline (121.174 us; speedup 1.0000x reference)
//
#include <hip/hip_runtime.h>
#include <hip/hip_bf16.h>

// Problem constants (fixed by reference)
#define NB    2
#define CIN   3
#define COUT  32
#define HDIM  160
#define WDIM  160
#define HW    25600      // HDIM*WDIM
#define NSTG  9

// ---------------- head: xh_t[b][s][c] = relu(sum_c x*head_w), channel-last ----
__global__ __launch_bounds__(256) void head_kernel(const float* __restrict__ x,
                                                   const float* __restrict__ head_w,
                                                   float* __restrict__ xh_t) {
    int idx = blockIdx.x * 256 + threadIdx.x;      // idx = (b*HW+s)*32 + o
    int o  = idx & 31;
    int bs = idx >> 5;                              // b*HW + s
    int b  = bs / HW;
    int s  = bs - b * HW;
    float acc = 0.f;
#pragma unroll
    for (int c = 0; c < CIN; ++c)
        acc += x[(b * CIN + c) * HW + s] * head_w[o * CIN + c];
    xh_t[idx] = fmaxf(acc, 0.f);
}

// ---------------- cross-lane: sum over each 32-lane half, broadcast to all ----
template <int CTRL>
__device__ __forceinline__ float dpp_add(float v) {
    int moved = __builtin_amdgcn_update_dpp(0, __float_as_int(v), CTRL, 0xf, 0xf, true);
    return v + __int_as_float(moved);
}

__device__ __forceinline__ float reduce32(float v) {
    v = dpp_add<0xB1>(v);   // quad_perm [1,0,3,2]  : xor 1
    v = dpp_add<0x4E>(v);   // quad_perm [2,3,0,1]  : xor 2
    v = dpp_add<0x124>(v);  // row_ror:4
    v = dpp_add<0x128>(v);  // row_ror:8  -> every lane has its row-of-16 sum
    int sw = __builtin_amdgcn_ds_swizzle(__float_as_int(v), 0x401F); // lane ^ 16
    return v + __int_as_float(sw);
}

// ---------------- main solver: one wave = 2 pixels, 32 channel-lanes each ----
__global__ __launch_bounds__(256) void solve_kernel(const float* __restrict__ xh_t,
                                                    const float* __restrict__ tail_w,
                                                    const float* __restrict__ alphas,
                                                    const float* __restrict__ betas,
                                                    float* __restrict__ out) {
    int tid  = blockIdx.x * 256 + threadIdx.x;
    int wv   = tid >> 6;
    int lane = threadIdx.x & 63;
    int c    = lane & 31;
    int pid  = wv * 2 + (lane >> 5);     // pixel id in [0, NB*HW)
    int b    = pid / HW;
    int s2   = pid - b * HW;

    // Gather X[k]: torch-unfold+reshape scramble, channel-preserving.
    const float* base = xh_t + (b * HW) * 32 + c;
    float X[9];
#pragma unroll
    for (int k2 = 0; k2 < 9; ++k2) {
        int g  = s2 * 9 + k2;
        int kk = g / HW;                 // 0..8
        int l  = g - kk * HW;
        int h  = l / WDIM;
        int w  = l - h * WDIM;
        int hh = min(max(h + kk / 3 - 1, 0), HDIM - 1);
        int ww = min(max(w + kk % 3 - 1, 0), WDIM - 1);
        X[k2] = base[(hh * WDIM + ww) * 32];
    }

    // init: u[c] = mean_k X ; v[k] = mean_c X
    float u = X[0];
#pragma unroll
    for (int k = 1; k < 9; ++k) u += X[k];
    u *= (1.f / 9.f);
    float v[9];
#pragma unroll
    for (int k = 0; k < 9; ++k) v[k] = reduce32(X[k]) * (1.f / 32.f);

    // 9 stages (rank-collapsed: all 3 ranks provably identical)
    for (int i = 0; i < NSTG; ++i) {
        float beta  = betas[i];
        float alpha = alphas[i];
        float s = reduce32(u * u);
#pragma unroll
        for (int k = 0; k < 9; ++k) {
            float q = reduce32(u * X[k]);
            v[k] = v[k] - beta * (3.f * s * v[k] - q);
        }
        float t = 0.f, m = 0.f;
#pragma unroll
        for (int k = 0; k < 9; ++k) {
            t += v[k] * v[k];
            m += X[k] * v[k];
        }
        u = u - alpha * (3.f * t * u - m);
    }

    // epilogue: UVc[c] = 3*u*v[center=4]; out[o] = relu(sum_c UVc * tail_w[o,c])
    float uvc = 3.f * u * v[4];
    float o0 = reduce32(uvc * tail_w[c]);
    float o1 = reduce32(uvc * tail_w[32 + c]);
    float o2 = reduce32(uvc * tail_w[64 + c]);
    if (c == 0) {
        float* op = out + b * 3 * HW + s2;
        op[0]      = fmaxf(o0, 0.f);
        op[HW]     = fmaxf(o1, 0.f);
        op[2 * HW] = fmaxf(o2, 0.f);
    }
}

extern "C" void kernel_launch(void* const* d_in, const int* in_sizes, int n_in,
                              void* d_out, int out_size, void* d_ws, size_t ws_size,
                              hipStream_t stream) {
    const float* x      = (const float*)d_in[0];
    const float* head_w = (const float*)d_in[1];
    const float* tail_w = (const float*)d_in[2];
    const float* alphas = (const float*)d_in[3];
    const float* betas  = (const float*)d_in[4];
    float*       out    = (float*)d_out;
    float*       xh_t   = (float*)d_ws;          // NB*HW*COUT floats = 6.55 MB

    // head: NB*HW*COUT = 1,638,400 threads
    head_kernel<<<dim3((NB * HW * COUT) / 256), dim3(256), 0, stream>>>(x, head_w, xh_t);
    // solve: NB*HW pixels, 2 per wave, 4 waves per block -> 6400 blocks
    solve_kernel<<<dim3((NB * HW) / 8), dim3(256), 0, stream>>>(xh_t, tail_w, alphas, betas, out);
}

// Round 2
// 78.495 us; speedup vs baseline: 1.5437x; 1.5437x over previous
//
#include <hip/hip_runtime.h>
#include <hip/hip_bf16.h>

// Problem constants (fixed by reference)
#define NB    2
#define HW    25600      // 160*160
#define WDIM  160
#define NSTG  9

// ---- DPP add over quads (full-rate VALU, no LDS) ----
template <int CTRL>
__device__ __forceinline__ float dpp_add(float v) {
    int moved = __builtin_amdgcn_update_dpp(0, __float_as_int(v), CTRL, 0xf, 0xf, true);
    return v + __int_as_float(moved);
}

// sum over each 8-lane group, broadcast to all 8 lanes
__device__ __forceinline__ float reduce8(float v) {
    v = dpp_add<0xB1>(v);   // quad_perm [1,0,3,2] : xor 1
    v = dpp_add<0x4E>(v);   // quad_perm [2,3,0,1] : xor 2
    int sw = __builtin_amdgcn_ds_swizzle(__float_as_int(v), 0x101F); // lane ^ 4
    return v + __int_as_float(sw);
}

// One fused kernel: head 1x1 conv (recomputed per gather position),
// rank-collapsed 9-stage iteration, tail 1x1 conv.
// Layout: 8 lanes per pixel, 4 channels per lane -> 8 pixels/wave.
__global__ __launch_bounds__(256) void fused_kernel(const float* __restrict__ x,
                                                    const float* __restrict__ head_w,
                                                    const float* __restrict__ tail_w,
                                                    const float* __restrict__ alphas,
                                                    const float* __restrict__ betas,
                                                    float* __restrict__ out) {
    int tid = blockIdx.x * 256 + threadIdx.x;
    int sub = threadIdx.x & 7;          // channel group: channels 4*sub .. 4*sub+3
    int pid = tid >> 3;                 // pixel id in [0, NB*HW)
    int b   = blockIdx.x / 800;         // 32 pixels/block -> 800 blocks per batch
    int s2  = pid - b * HW;

    // head weights for my 4 channels: head_w is [32][3], rows c0..c0+3 contiguous
    int c0 = sub * 4;
    float hw[4][3];
#pragma unroll
    for (int j = 0; j < 4; ++j)
#pragma unroll
        for (int ci = 0; ci < 3; ++ci)
            hw[j][ci] = head_w[(c0 + j) * 3 + ci];

    const float* xb = x + b * 3 * HW;

    // Gather X[k][j] through the torch-unfold+reshape scramble (channel-preserving),
    // computing the head conv on the fly for each of the 9 scrambled positions.
    float X[9][4];
    int g9  = s2 * 9;
    int kk0 = g9 / HW;
    int r0  = g9 - kk0 * HW;
    int h0  = r0 / WDIM;
    int w0  = r0 - h0 * WDIM;
#pragma unroll
    for (int k2 = 0; k2 < 9; ++k2) {
        int r    = r0 + k2;
        int wrap = (r >= HW);
        int wn   = w0 + k2;
        int cw   = (wn >= WDIM);
        int w_nw = wn - (cw ? WDIM : 0);
        int h_nw = h0 + cw;
        int h    = wrap ? 0 : h_nw;
        int w    = wrap ? (r - HW) : w_nw;
        int kk   = kk0 + wrap;          // 0..8
        int ki   = kk / 3;
        int kj   = kk - ki * 3;
        int hh   = min(max(h + ki - 1, 0), 159);
        int ww   = min(max(w + kj - 1, 0), 159);
        int p    = hh * WDIM + ww;
        float x0 = xb[p], x1 = xb[HW + p], x2 = xb[2 * HW + p];
#pragma unroll
        for (int j = 0; j < 4; ++j)
            X[k2][j] = fmaxf(hw[j][0] * x0 + hw[j][1] * x1 + hw[j][2] * x2, 0.f);
    }

    // init: u[c] = mean_k X ; v[k] = mean_c X
    float u[4];
#pragma unroll
    for (int j = 0; j < 4; ++j) {
        float a = X[0][j];
#pragma unroll
        for (int k = 1; k < 9; ++k) a += X[k][j];
        u[j] = a * (1.f / 9.f);
    }
    float v[9];
#pragma unroll
    for (int k = 0; k < 9; ++k) {
        float pr = (X[k][0] + X[k][1]) + (X[k][2] + X[k][3]);
        v[k] = reduce8(pr) * (1.f / 32.f);
    }

    // 9 stages (rank-collapsed: all 3 ranks provably identical)
#pragma unroll
    for (int i = 0; i < NSTG; ++i) {
        float beta  = betas[i];
        float alpha = alphas[i];
        float sp = (u[0] * u[0] + u[1] * u[1]) + (u[2] * u[2] + u[3] * u[3]);
        float s  = reduce8(sp);
        float vs = 1.f - 3.f * beta * s;
#pragma unroll
        for (int k = 0; k < 9; ++k) {
            float qp = (u[0] * X[k][0] + u[1] * X[k][1]) + (u[2] * X[k][2] + u[3] * X[k][3]);
            float q  = reduce8(qp);
            v[k] = v[k] * vs + beta * q;
        }
        float t = 0.f;
#pragma unroll
        for (int k = 0; k < 9; ++k) t += v[k] * v[k];
        float us = 1.f - 3.f * alpha * t;
#pragma unroll
        for (int j = 0; j < 4; ++j) {
            float m = 0.f;
#pragma unroll
            for (int k = 0; k < 9; ++k) m += X[k][j] * v[k];
            u[j] = u[j] * us + alpha * m;
        }
    }

    // epilogue: UVc[c] = 3*u[c]*v[center=4]; out[o] = relu(sum_c UVc * tail_w[o*32+c])
    float v4 = v[4];
    float uvc[4];
#pragma unroll
    for (int j = 0; j < 4; ++j) uvc[j] = 3.f * u[j] * v4;
    float o[3];
#pragma unroll
    for (int oo = 0; oo < 3; ++oo) {
        const float* tw = tail_w + oo * 32 + c0;
        float pr = (uvc[0] * tw[0] + uvc[1] * tw[1]) + (uvc[2] * tw[2] + uvc[3] * tw[3]);
        o[oo] = fmaxf(reduce8(pr), 0.f);
    }
    if (sub == 0) {
        float* op = out + b * 3 * HW + s2;
        op[0]      = o[0];
        op[HW]     = o[1];
        op[2 * HW] = o[2];
    }
}

extern "C" void kernel_launch(void* const* d_in, const int* in_sizes, int n_in,
                              void* d_out, int out_size, void* d_ws, size_t ws_size,
                              hipStream_t stream) {
    const float* x      = (const float*)d_in[0];
    const float* head_w = (const float*)d_in[1];
    const float* tail_w = (const float*)d_in[2];
    const float* alphas = (const float*)d_in[3];
    const float* betas  = (const float*)d_in[4];
    float*       out    = (float*)d_out;

    // NB*HW pixels * 8 lanes/pixel = 409600 threads -> 1600 blocks of 256
    fused_kernel<<<dim3(NB * HW * 8 / 256), dim3(256), 0, stream>>>(
        x, head_w, tail_w, alphas, betas, out);
}